// Round 7
// baseline (213.917 us; speedup 1.0000x reference)
//
#include <hip/hip_runtime.h>
#include <hip/hip_bf16.h>

// Problem constants
#define BATCH 16384
#define F1    1024
#define F2    512
#define NCLS  64
#define NEXP  8
#define BPAD  (BATCH + NEXP*128)  // 17408 (segments padded to 128)
#define NBM   136                 // BPAD/128 gemm1 m-blocks
#define NBG1  544                 // NBM * 4 strips
#define NBG2  272                 // BPAD/64 gemm2 m-blocks

typedef __attribute__((ext_vector_type(8))) short short8;   // 8 bf16
typedef __attribute__((ext_vector_type(4))) float float4v;  // MFMA C/D
typedef __attribute__((ext_vector_type(4))) unsigned uint4v;

// Workspace layout (bytes) — kept identical to prior rounds (xp regions now unused)
#define O_META   0
#define O_BEXP   4096
#define O_ORDER  8192
#define O_XPH    131072
#define O_XPL    (O_XPH + 35651584)
#define O_W1H    (O_XPL + 35651584)      // [8 e][4 strip][32 ks][4 q][128 n][8]
#define O_W1L    (O_W1H + 8388608)
#define O_W2H    (O_W1L + 8388608)       // [8 e][8 ks][8 q][64 c][8]
#define O_W2L    (O_W2H + 524288)
#define O_HH     (O_W2L + 524288)        // packed h hi tiles: [272 mb2][8 ks][8 q][64 r][8]
#define O_HL     (O_HH + 17825792)

__device__ inline short bf16_rn(float f) {
    unsigned u = __builtin_bit_cast(unsigned, f);
    u = (u + 0x7fffu + ((u >> 16) & 1u)) >> 16;
    return (short)u;
}
__device__ inline float bf16_up(short h) {
    return __builtin_bit_cast(float, ((unsigned)(unsigned short)h) << 16);
}
__device__ inline void split2(float v, short& hi, short& lo) {
    hi = bf16_rn(v);
    lo = bf16_rn(v - bf16_up(hi));
}
__device__ inline float4v mfma16(short8 a, short8 b, float4v c) {
    return __builtin_amdgcn_mfma_f32_16x16x32_bf16(a, b, c, 0, 0, 0);
}
__device__ inline void glds16(const void* g, void* l) {
    __builtin_amdgcn_global_load_lds((const __attribute__((address_space(1))) void*)g,
                                     (__attribute__((address_space(3))) void*)l,
                                     16, 0, 0);
}
// packed RNE f32->bf16 pair; identical values to split2's RNE
__device__ inline unsigned cvt_pk_bf16(float a, float b) {
    __hip_bfloat162 h = __float22bfloat162_rn(make_float2(a, b));
    union { __hip_bfloat162 v; unsigned u; } cv;
    cv.v = h;
    return cv.u;  // low16 = bf16(a), high16 = bf16(b)
}
// 8 f32 -> hi/lo bf16x8. Builds short8 by bit-casting 4 packed cvt_pk words
// directly (no per-lane short extraction => no pack/unpack VALU on the
// split->MFMA dependency chain). Values identical to split2's RNE.
__device__ inline void splitA8(const float4& r0, const float4& r1, short8& vh, short8& vl) {
    const unsigned u0 = cvt_pk_bf16(r0.x, r0.y);
    const unsigned u1 = cvt_pk_bf16(r0.z, r0.w);
    const unsigned u2 = cvt_pk_bf16(r1.x, r1.y);
    const unsigned u3 = cvt_pk_bf16(r1.z, r1.w);
    uint4v uh = {u0, u1, u2, u3};
    vh = __builtin_bit_cast(short8, uh);
    const unsigned l0 = cvt_pk_bf16(r0.x - __builtin_bit_cast(float, u0 << 16),
                                    r0.y - __builtin_bit_cast(float, u0 & 0xFFFF0000u));
    const unsigned l1 = cvt_pk_bf16(r0.z - __builtin_bit_cast(float, u1 << 16),
                                    r0.w - __builtin_bit_cast(float, u1 & 0xFFFF0000u));
    const unsigned l2 = cvt_pk_bf16(r1.x - __builtin_bit_cast(float, u2 << 16),
                                    r1.y - __builtin_bit_cast(float, u2 & 0xFFFF0000u));
    const unsigned l3 = cvt_pk_bf16(r1.z - __builtin_bit_cast(float, u3 << 16),
                                    r1.w - __builtin_bit_cast(float, u3 & 0xFFFF0000u));
    uint4v ul = {l0, l1, l2, l3};
    vl = __builtin_bit_cast(short8, ul);
}

// ---------------- init+Wpack mega-kernel: order=-1, histogram, W1/W2 -> 8KB tiles ----------------
#define NPW1 1024  // 8 e x 4 strip x 32 ks
#define NPW2 64    // 8 e x 8 ks
__global__ __launch_bounds__(256)
void dael_init_pack(const int* __restrict__ domain, int* meta, int* order,
                    const float* __restrict__ W1, short* w1h, short* w1l,
                    const float* __restrict__ W2, short* w2h, short* w2l) {
    __shared__ int hc[NEXP];
    const int b = blockIdx.x, t = threadIdx.x;
    // init roles (first 68 blocks)
    if (b < 68) {
        const int i = b * 256 + t;
        if (i < BPAD) order[i] = -1;
    }
    if (b < 64) {
        if (t < NEXP) hc[t] = 0;
        __syncthreads();
        atomicAdd(&hc[domain[b * 256 + t]], 1);
        __syncthreads();
        if (t < NEXP) meta[64 + b * NEXP + t] = hc[t];
    }
    // W pack roles (all 1088 blocks)
    if (b < NPW1) {
        const int e = b >> 7, strip = (b >> 5) & 3, ks = b & 31;
        const size_t tb = (size_t)((e * 4 + strip) * 32 + ks) * 4096;
        #pragma unroll
        for (int sl = 0; sl < 2; ++sl) {
            const int s = t + sl * 256;
            const int q = s >> 7, r = s & 127;
            const int n = strip * 128 + r;
            short8 vh, vl;
            #pragma unroll
            for (int jj = 0; jj < 8; ++jj) {
                const int k = ks * 32 + q * 8 + jj;
                float v = W1[((size_t)(e * F1 + k)) * F2 + n];
                short h, l; split2(v, h, l); vh[jj] = h; vl[jj] = l;
            }
            *(short8*)(w1h + tb + s * 8) = vh;
            *(short8*)(w1l + tb + s * 8) = vl;
        }
    } else {
        const int b3 = b - NPW1;
        const int e = b3 >> 3, ks = b3 & 7;
        const size_t tb = (size_t)(e * 8 + ks) * 4096;
        #pragma unroll
        for (int sl = 0; sl < 2; ++sl) {
            const int s = t + sl * 256;
            const int q = s >> 6, c = s & 63;
            short8 vh, vl;
            #pragma unroll
            for (int jj = 0; jj < 8; ++jj) {
                const int k = ks * 64 + q * 8 + jj;
                float v = W2[((size_t)(e * F2 + k)) * NCLS + c];
                short h, l; split2(v, h, l); vh[jj] = h; vl[jj] = l;
            }
            *(short8*)(w2h + tb + s * 8) = vh;
            *(short8*)(w2l + tb + s * 8) = vl;
        }
    }
}

// ---------------- plan: sum partials, bases/cursors, bexp (1 block) ----------------
__global__ void dael_plan(int* meta, int* bexp) {
    __shared__ int cnt[NEXP], soff[NEXP + 1];
    const int t = threadIdx.x;
    if (t < NEXP) {
        int s = 0;
        for (int b = 0; b < 64; ++b) s += meta[64 + b * NEXP + t];
        cnt[t] = s;
    }
    __syncthreads();
    if (t == 0) {
        int acc = 0;
        for (int e = 0; e < NEXP; ++e) {
            soff[e] = acc;
            meta[16 + e] = acc * 128;  // padded row base
            meta[8 + e] = 0;           // cursor
            acc += (cnt[e] + 127) >> 7;
        }
        soff[NEXP] = acc;
    }
    __syncthreads();
    for (int i = t; i < NBM; i += 256) {
        int ee = -1;
        #pragma unroll
        for (int e = 0; e < NEXP; ++e)
            if (i >= soff[e] && i < soff[e + 1]) ee = e;
        bexp[i] = ee;
    }
}

// ---------------- scatter: per-block LDS ranks ----------------
__global__ void dael_scatter(const int* __restrict__ domain, int* meta, int* order) {
    __shared__ int lc[NEXP], lb[NEXP];
    const int t = threadIdx.x;
    const int i = blockIdx.x * 256 + t;
    if (t < NEXP) lc[t] = 0;
    __syncthreads();
    const int d = domain[i];
    const int r = atomicAdd(&lc[d], 1);
    __syncthreads();
    if (t < NEXP && lc[t] > 0) lb[t] = atomicAdd(&meta[8 + t], lc[t]);
    __syncthreads();
    order[meta[16 + d] + lb[d] + r] = i;
}

// ---------------- GEMM1: 128x128, BK=32 ----------------
// v7 = v6 with two latency fixes:
//  (1) A-refill loads issued at TOP of iteration (right after the B glds), not at
//      the end: the in-order vmcnt ledger [Gb,Ra,Gb,Ra] is unchanged, but A's
//      deadline-to-issue distance grows from ~1.2 to 2.0 iterations (~1000cyc),
//      covering scattered-gather L3/HBM latency. Loads go to temp regs (nra),
//      committed to the RA slot after the split consumes the old value.
//  (2) splitA8 builds MFMA operands from packed cvt_pk words via bitcast (no
//      per-lane short extraction) — halves the serial VALU in front of MFMA.
// B: triple-buffered LDS (3x16KB); counted s_waitcnt vmcnt(8); vmcnt(0) @ks=31.
__global__ __launch_bounds__(256, 3)
void dael_gemm1(const int* __restrict__ order, const int* __restrict__ bexp,
                const float* __restrict__ x,
                const short* __restrict__ w1h, const short* __restrict__ w1l,
                const float* __restrict__ b1,
                short* __restrict__ hh, short* __restrict__ hl) {
    const int L = blockIdx.x;
    const int xcd = L & 7, j = L >> 3;
    const int mb = xcd * 17 + (j % 17);
    const int strip = j / 17;
    const int e = bexp[mb];
    if (e < 0) return;
    const int tid = threadIdx.x;
    const int lane = tid & 63, wv = tid >> 6;
    const int quad = lane >> 4, lrow = lane & 15;
    const int r0w = wv * 32;   // wave owns rows [r0w, r0w+32), all 128 cols

    // 3 x 16KB B buffers; epilogue T[128][136] (34816B) reuses
    __shared__ __align__(16) char SMc[49152];

    // A: per-lane sample rows (clamp pad rows to 0 — garbage-but-finite h rows;
    // gemm2 masks the final store by samp>=0)
    int s0 = order[mb * 128 + r0w + lrow];
    int s1 = order[mb * 128 + r0w + 16 + lrow];
    if (s0 < 0) s0 = 0;
    if (s1 < 0) s1 = 0;
    const float* xb0 = x + (size_t)s0 * F1 + quad * 8;
    const float* xb1 = x + (size_t)s1 * F1 + quad * 8;
    // B: staged via global_load_lds
    const short* Bh = w1h + (size_t)((e * 4 + strip) * 32) * 4096 + tid * 8;
    const short* Bl = w1l + (size_t)((e * 4 + strip) * 32) * 4096 + tid * 8;
    const int d0 = tid * 16;

    float4v acc[2][8] = {};
    int offb[8];
    #pragma unroll
    for (int jj = 0; jj < 8; ++jj) offb[jj] = quad * 2048 + (jj * 16 + lrow) * 16;

    float4 ra0[4], ra1[4];
    int c0 = 0, c1 = 16384, c2 = 32768;  // rotating LDS buffer byte offsets

    // prologue, issue order pinned: B(0) glds x4, A(0) x4, B(1) glds x4, A(1) x4
    glds16(Bh,        SMc + d0);
    glds16(Bh + 2048, SMc + 4096 + d0);
    glds16(Bl,        SMc + 8192 + d0);
    glds16(Bl + 2048, SMc + 12288 + d0);
    asm volatile("" ::: "memory");
    ra0[0] = *(const float4*)(xb0);
    ra0[1] = *(const float4*)(xb0 + 4);
    ra0[2] = *(const float4*)(xb1);
    ra0[3] = *(const float4*)(xb1 + 4);
    asm volatile("" ::: "memory");
    glds16(Bh + 4096,        SMc + 16384 + d0);
    glds16(Bh + 4096 + 2048, SMc + 16384 + 4096 + d0);
    glds16(Bl + 4096,        SMc + 16384 + 8192 + d0);
    glds16(Bl + 4096 + 2048, SMc + 16384 + 12288 + d0);
    asm volatile("" ::: "memory");
    ra1[0] = *(const float4*)(xb0 + 32);
    ra1[1] = *(const float4*)(xb0 + 36);
    ra1[2] = *(const float4*)(xb1 + 32);
    ra1[3] = *(const float4*)(xb1 + 36);

#define G1_ITER(KS, RA)                                                        \
    {                                                                          \
        if ((KS) == 31) { asm volatile("s_waitcnt vmcnt(0)" ::: "memory"); }   \
        else            { asm volatile("s_waitcnt vmcnt(8)" ::: "memory"); }   \
        __builtin_amdgcn_s_barrier();                                          \
        asm volatile("" ::: "memory");                                         \
        if ((KS) + 2 < 32) {                                                   \
            const int so_ = ((KS) + 2) * 4096;                                 \
            glds16(Bh + so_,        SMc + c2 + d0);                            \
            glds16(Bh + so_ + 2048, SMc + c2 + 4096 + d0);                     \
            glds16(Bl + so_,        SMc + c2 + 8192 + d0);                     \
            glds16(Bl + so_ + 2048, SMc + c2 + 12288 + d0);                    \
        }                                                                      \
        asm volatile("" ::: "memory");                                         \
        float4 nra0, nra1, nra2, nra3;                                         \
        if ((KS) + 2 < 32) {                                                   \
            const int ao_ = ((KS) + 2) * 32;                                   \
            nra0 = *(const float4*)(xb0 + ao_);                                \
            nra1 = *(const float4*)(xb0 + ao_ + 4);                            \
            nra2 = *(const float4*)(xb1 + ao_);                                \
            nra3 = *(const float4*)(xb1 + ao_ + 4);                            \
        }                                                                      \
        asm volatile("" ::: "memory");                                         \
        short8 ah[2], al[2];                                                   \
        splitA8(RA[0], RA[1], ah[0], al[0]);                                   \
        splitA8(RA[2], RA[3], ah[1], al[1]);                                   \
        __builtin_amdgcn_s_setprio(1);                                         \
        _Pragma("unroll")                                                      \
        for (int jj = 0; jj < 8; ++jj) {                                       \
            short8 bh = *(const short8*)(SMc + c0 + offb[jj]);                 \
            short8 bl = *(const short8*)(SMc + c0 + 8192 + offb[jj]);          \
            _Pragma("unroll")                                                  \
            for (int i = 0; i < 2; ++i) {                                      \
                acc[i][jj] = mfma16(ah[i], bh, acc[i][jj]);                    \
                acc[i][jj] = mfma16(ah[i], bl, acc[i][jj]);                    \
                acc[i][jj] = mfma16(al[i], bh, acc[i][jj]);                    \
            }                                                                  \
        }                                                                      \
        __builtin_amdgcn_s_setprio(0);                                         \
        if ((KS) + 2 < 32) {                                                   \
            RA[0] = nra0; RA[1] = nra1; RA[2] = nra2; RA[3] = nra3;            \
        }                                                                      \
        { const int tmp_ = c0; c0 = c1; c1 = c2; c2 = tmp_; }                  \
    }

    for (int kb = 0; kb < 32; kb += 2) {
        G1_ITER(kb,     ra0);
        G1_ITER(kb + 1, ra1);
    }
#undef G1_ITER

    // epilogue: +b1, relu, split; through LDS T[128][136]; store packed h tiles
    float bv[8];
    #pragma unroll
    for (int jj = 0; jj < 8; ++jj)
        bv[jj] = b1[e * F2 + strip * 128 + jj * 16 + lrow];
    short* T = (short*)SMc;
    #pragma unroll
    for (int plane = 0; plane < 2; ++plane) {
        __syncthreads();
        #pragma unroll
        for (int i = 0; i < 2; ++i)
            #pragma unroll
            for (int jj = 0; jj < 8; ++jj)
                #pragma unroll
                for (int r = 0; r < 4; ++r) {
                    const int m = r0w + i * 16 + quad * 4 + r;
                    const int n = jj * 16 + lrow;
                    float hv = fmaxf(acc[i][jj][r] + bv[jj], 0.f);
                    short hi = bf16_rn(hv);
                    T[m * 136 + n] = plane ? bf16_rn(hv - bf16_up(hi)) : hi;
                }
        __syncthreads();
        short* dst = plane ? hl : hh;
        #pragma unroll
        for (int u = 0; u < 8; ++u) {
            const int sidx = tid + 256 * u;          // 0..2047
            const int g = sidx >> 6, m64 = sidx & 63;
            const int mloc = g >> 4, ksl = (g >> 3) & 1, q = g & 7;
            const int m = mloc * 64 + m64;
            const int n = ksl * 64 + q * 8;
            const size_t off = ((size_t)((mb * 2 + mloc) * 8 + strip * 2 + ksl)) * 4096
                               + q * 512 + m64 * 8;
            *(short8*)(dst + off) = *(const short8*)&T[m * 136 + n];
        }
    }
}

// ---------------- GEMM2: 64x64, BK=64, double-buffered; softmax ----------------
__global__ __launch_bounds__(256)
void dael_gemm2(const int* __restrict__ order, const int* __restrict__ bexp,
                const short* __restrict__ hh, const short* __restrict__ hl,
                const short* __restrict__ w2h, const short* __restrict__ w2l,
                const float* __restrict__ b2, float* __restrict__ out) {
    const int b = blockIdx.x;
    const int e = bexp[b >> 1];
    if (e < 0) return;
    const int p0 = b * 64;
    const int tid = threadIdx.x;
    const int lane = tid & 63, wv = tid >> 6;
    const int quad = lane >> 4, lrow = lane & 15;

    __shared__ __align__(16) char SM2[65536];  // 2 x 32KB double buffer; softmax reuses
    __shared__ float inv[64];

    const short* Ah = hh + (size_t)(b * 8) * 4096 + tid * 8;
    const short* Al = hl + (size_t)(b * 8) * 4096 + tid * 8;
    const short* Bh = w2h + (size_t)(e * 8) * 4096 + tid * 8;
    const short* Bl = w2l + (size_t)(e * 8) * 4096 + tid * 8;
    const int d0 = tid * 16;

    float4v acc[4] = {};

    {
        glds16(Ah,        SM2 + d0);
        glds16(Ah + 2048, SM2 + 4096 + d0);
        glds16(Al,        SM2 + 8192 + d0);
        glds16(Al + 2048, SM2 + 12288 + d0);
        glds16(Bh,        SM2 + 16384 + d0);
        glds16(Bh + 2048, SM2 + 20480 + d0);
        glds16(Bl,        SM2 + 24576 + d0);
        glds16(Bl + 2048, SM2 + 28672 + d0);
    }

    for (int ks = 0; ks < 8; ++ks) {
        __syncthreads();
        if (ks + 1 < 8) {
            const int so = (ks + 1) * 4096;
            const int db = ((ks + 1) & 1) * 32768;
            glds16(Ah + so,        SM2 + db + d0);
            glds16(Ah + so + 2048, SM2 + db + 4096 + d0);
            glds16(Al + so,        SM2 + db + 8192 + d0);
            glds16(Al + so + 2048, SM2 + db + 12288 + d0);
            glds16(Bh + so,        SM2 + db + 16384 + d0);
            glds16(Bh + so + 2048, SM2 + db + 20480 + d0);
            glds16(Bl + so,        SM2 + db + 24576 + d0);
            glds16(Bl + so + 2048, SM2 + db + 28672 + d0);
        }
        const int db = (ks & 1) * 32768;
        #pragma unroll
        for (int ksub = 0; ksub < 2; ++ksub) {
            const int qa = (ksub * 4 + quad) * 1024;
            const int ao = db + qa + (wv * 16 + lrow) * 16;
            short8 ahf = *(const short8*)(SM2 + ao);
            short8 alf = *(const short8*)(SM2 + 8192 + ao);
            #pragma unroll
            for (int jj = 0; jj < 4; ++jj) {
                const int bo = db + 16384 + qa + (jj * 16 + lrow) * 16;
                short8 bh = *(const short8*)(SM2 + bo);
                short8 bl = *(const short8*)(SM2 + 8192 + bo);
                acc[jj] = mfma16(ahf, bh, acc[jj]);
                acc[jj] = mfma16(ahf, bl, acc[jj]);
                acc[jj] = mfma16(alf, bh, acc[jj]);
            }
        }
    }

    __syncthreads();
    float* Lx = (float*)SM2;               // [64][68]
    #pragma unroll
    for (int jj = 0; jj < 4; ++jj) {
        const int n = jj * 16 + lrow;
        const float bb = b2[e * NCLS + n];
        #pragma unroll
        for (int r = 0; r < 4; ++r)
            Lx[(wv * 16 + quad * 4 + r) * 68 + n] = acc[jj][r] + bb;
    }
    __syncthreads();
    if (tid < 64) {
        float mx = -3.402823466e38f;
        #pragma unroll 8
        for (int c = 0; c < NCLS; ++c) mx = fmaxf(mx, Lx[tid * 68 + c]);
        float s = 0.f;
        #pragma unroll 8
        for (int c = 0; c < NCLS; ++c) {
            float ev = __expf(Lx[tid * 68 + c] - mx);
            Lx[tid * 68 + c] = ev; s += ev;
        }
        inv[tid] = 1.f / s;
    }
    __syncthreads();
    const int r = tid >> 2, cs = (tid & 3) * 16;
    const int samp = order[p0 + r];
    if (samp >= 0) {
        const float sc = inv[r];
        #pragma unroll
        for (int q = 0; q < 4; ++q) {
            float4 v = *(const float4*)&Lx[r * 68 + cs + q * 4];
            v.x *= sc; v.y *= sc; v.z *= sc; v.w *= sc;
            *(float4*)(out + (size_t)samp * NCLS + cs + q * 4) = v;
        }
    }
}

extern "C" void kernel_launch(void* const* d_in, const int* in_sizes, int n_in,
                              void* d_out, int out_size, void* d_ws, size_t ws_size,
                              hipStream_t stream) {
    const int*   domain = (const int*)d_in[0];
    const float* x      = (const float*)d_in[1];
    const float* W1     = (const float*)d_in[2];
    const float* b1     = (const float*)d_in[3];
    const float* W2     = (const float*)d_in[4];
    const float* b2     = (const float*)d_in[5];
    float* out = (float*)d_out;

    char* ws = (char*)d_ws;
    int*   meta  = (int*)(ws + O_META);
    int*   bexp  = (int*)(ws + O_BEXP);
    int*   order = (int*)(ws + O_ORDER);
    short* w1h   = (short*)(ws + O_W1H);
    short* w1l   = (short*)(ws + O_W1L);
    short* w2h   = (short*)(ws + O_W2H);
    short* w2l   = (short*)(ws + O_W2L);
    short* hh    = (short*)(ws + O_HH);
    short* hl    = (short*)(ws + O_HL);

    dael_init_pack<<<NPW1 + NPW2, 256, 0, stream>>>(domain, meta, order,
                                                    W1, w1h, w1l, W2, w2h, w2l);
    dael_plan<<<1, 256, 0, stream>>>(meta, bexp);
    dael_scatter<<<64, 256, 0, stream>>>(domain, meta, order);
    dael_gemm1<<<NBG1, 256, 0, stream>>>(order, bexp, x, w1h, w1l, b1, hh, hl);
    dael_gemm2<<<NBG2, 256, 0, stream>>>(order, bexp, hh, hl, w2h, w2l, b2, out);
}

// Round 8
// 200.936 us; speedup vs baseline: 1.0646x; 1.0646x over previous
//
#include <hip/hip_runtime.h>
#include <hip/hip_bf16.h>

// Problem constants
#define BATCH 16384
#define F1    1024
#define F2    512
#define NCLS  64
#define NEXP  8
#define BPAD  (BATCH + NEXP*128)  // 17408 (segments padded to 128)
#define NBM   136                 // BPAD/128 gemm1 m-blocks
#define NBG1  544                 // NBM * 4 strips
#define NBG2  272                 // BPAD/64 gemm2 m-blocks

typedef __attribute__((ext_vector_type(8))) short short8;   // 8 bf16
typedef __attribute__((ext_vector_type(4))) float float4v;  // MFMA C/D
typedef __attribute__((ext_vector_type(4))) unsigned uint4v;

// Workspace layout (bytes) — kept identical to prior rounds (xp regions now unused)
#define O_META   0
#define O_BEXP   4096
#define O_ORDER  8192
#define O_XPH    131072
#define O_XPL    (O_XPH + 35651584)
#define O_W1H    (O_XPL + 35651584)      // [8 e][4 strip][32 ks][4 q][128 n][8]
#define O_W1L    (O_W1H + 8388608)
#define O_W2H    (O_W1L + 8388608)       // [8 e][8 ks][8 q][64 c][8]
#define O_W2L    (O_W2H + 524288)
#define O_HH     (O_W2L + 524288)        // packed h hi tiles: [272 mb2][8 ks][8 q][64 r][8]
#define O_HL     (O_HH + 17825792)

__device__ inline short bf16_rn(float f) {
    unsigned u = __builtin_bit_cast(unsigned, f);
    u = (u + 0x7fffu + ((u >> 16) & 1u)) >> 16;
    return (short)u;
}
__device__ inline float bf16_up(short h) {
    return __builtin_bit_cast(float, ((unsigned)(unsigned short)h) << 16);
}
__device__ inline void split2(float v, short& hi, short& lo) {
    hi = bf16_rn(v);
    lo = bf16_rn(v - bf16_up(hi));
}
__device__ inline float4v mfma16(short8 a, short8 b, float4v c) {
    return __builtin_amdgcn_mfma_f32_16x16x32_bf16(a, b, c, 0, 0, 0);
}
__device__ inline void glds16(const void* g, void* l) {
    __builtin_amdgcn_global_load_lds((const __attribute__((address_space(1))) void*)g,
                                     (__attribute__((address_space(3))) void*)l,
                                     16, 0, 0);
}
// packed RNE f32->bf16 pair; identical values to split2's RNE
__device__ inline unsigned cvt_pk_bf16(float a, float b) {
    __hip_bfloat162 h = __float22bfloat162_rn(make_float2(a, b));
    union { __hip_bfloat162 v; unsigned u; } cv;
    cv.v = h;
    return cv.u;  // low16 = bf16(a), high16 = bf16(b)
}
// 8 f32 -> hi/lo bf16x8 via packed words + bitcast (no per-lane short extraction).
// Values identical to split2's RNE.
__device__ inline void splitA8(const float4& r0, const float4& r1, short8& vh, short8& vl) {
    const unsigned u0 = cvt_pk_bf16(r0.x, r0.y);
    const unsigned u1 = cvt_pk_bf16(r0.z, r0.w);
    const unsigned u2 = cvt_pk_bf16(r1.x, r1.y);
    const unsigned u3 = cvt_pk_bf16(r1.z, r1.w);
    uint4v uh = {u0, u1, u2, u3};
    vh = __builtin_bit_cast(short8, uh);
    const unsigned l0 = cvt_pk_bf16(r0.x - __builtin_bit_cast(float, u0 << 16),
                                    r0.y - __builtin_bit_cast(float, u0 & 0xFFFF0000u));
    const unsigned l1 = cvt_pk_bf16(r0.z - __builtin_bit_cast(float, u1 << 16),
                                    r0.w - __builtin_bit_cast(float, u1 & 0xFFFF0000u));
    const unsigned l2 = cvt_pk_bf16(r1.x - __builtin_bit_cast(float, u2 << 16),
                                    r1.y - __builtin_bit_cast(float, u2 & 0xFFFF0000u));
    const unsigned l3 = cvt_pk_bf16(r1.z - __builtin_bit_cast(float, u3 << 16),
                                    r1.w - __builtin_bit_cast(float, u3 & 0xFFFF0000u));
    uint4v ul = {l0, l1, l2, l3};
    vl = __builtin_bit_cast(short8, ul);
}

// ---------------- init+Wpack mega-kernel: order=-1, histogram, W1/W2 -> 8KB tiles ----------------
#define NPW1 1024  // 8 e x 4 strip x 32 ks
#define NPW2 64    // 8 e x 8 ks
__global__ __launch_bounds__(256)
void dael_init_pack(const int* __restrict__ domain, int* meta, int* order,
                    const float* __restrict__ W1, short* w1h, short* w1l,
                    const float* __restrict__ W2, short* w2h, short* w2l) {
    __shared__ int hc[NEXP];
    const int b = blockIdx.x, t = threadIdx.x;
    // init roles (first 68 blocks)
    if (b < 68) {
        const int i = b * 256 + t;
        if (i < BPAD) order[i] = -1;
    }
    if (b < 64) {
        if (t < NEXP) hc[t] = 0;
        __syncthreads();
        atomicAdd(&hc[domain[b * 256 + t]], 1);
        __syncthreads();
        if (t < NEXP) meta[64 + b * NEXP + t] = hc[t];
    }
    // W pack roles (all 1088 blocks)
    if (b < NPW1) {
        const int e = b >> 7, strip = (b >> 5) & 3, ks = b & 31;
        const size_t tb = (size_t)((e * 4 + strip) * 32 + ks) * 4096;
        #pragma unroll
        for (int sl = 0; sl < 2; ++sl) {
            const int s = t + sl * 256;
            const int q = s >> 7, r = s & 127;
            const int n = strip * 128 + r;
            short8 vh, vl;
            #pragma unroll
            for (int jj = 0; jj < 8; ++jj) {
                const int k = ks * 32 + q * 8 + jj;
                float v = W1[((size_t)(e * F1 + k)) * F2 + n];
                short h, l; split2(v, h, l); vh[jj] = h; vl[jj] = l;
            }
            *(short8*)(w1h + tb + s * 8) = vh;
            *(short8*)(w1l + tb + s * 8) = vl;
        }
    } else {
        const int b3 = b - NPW1;
        const int e = b3 >> 3, ks = b3 & 7;
        const size_t tb = (size_t)(e * 8 + ks) * 4096;
        #pragma unroll
        for (int sl = 0; sl < 2; ++sl) {
            const int s = t + sl * 256;
            const int q = s >> 6, c = s & 63;
            short8 vh, vl;
            #pragma unroll
            for (int jj = 0; jj < 8; ++jj) {
                const int k = ks * 64 + q * 8 + jj;
                float v = W2[((size_t)(e * F2 + k)) * NCLS + c];
                short h, l; split2(v, h, l); vh[jj] = h; vl[jj] = l;
            }
            *(short8*)(w2h + tb + s * 8) = vh;
            *(short8*)(w2l + tb + s * 8) = vl;
        }
    }
}

// ---------------- plan: sum partials, bases/cursors, bexp (1 block) ----------------
__global__ void dael_plan(int* meta, int* bexp) {
    __shared__ int cnt[NEXP], soff[NEXP + 1];
    const int t = threadIdx.x;
    if (t < NEXP) {
        int s = 0;
        for (int b = 0; b < 64; ++b) s += meta[64 + b * NEXP + t];
        cnt[t] = s;
    }
    __syncthreads();
    if (t == 0) {
        int acc = 0;
        for (int e = 0; e < NEXP; ++e) {
            soff[e] = acc;
            meta[16 + e] = acc * 128;  // padded row base
            meta[8 + e] = 0;           // cursor
            acc += (cnt[e] + 127) >> 7;
        }
        soff[NEXP] = acc;
    }
    __syncthreads();
    for (int i = t; i < NBM; i += 256) {
        int ee = -1;
        #pragma unroll
        for (int e = 0; e < NEXP; ++e)
            if (i >= soff[e] && i < soff[e + 1]) ee = e;
        bexp[i] = ee;
    }
}

// ---------------- scatter: per-block LDS ranks ----------------
__global__ void dael_scatter(const int* __restrict__ domain, int* meta, int* order) {
    __shared__ int lc[NEXP], lb[NEXP];
    const int t = threadIdx.x;
    const int i = blockIdx.x * 256 + t;
    if (t < NEXP) lc[t] = 0;
    __syncthreads();
    const int d = domain[i];
    const int r = atomicAdd(&lc[d], 1);
    __syncthreads();
    if (t < NEXP && lc[t] > 0) lb[t] = atomicAdd(&meta[8 + t], lc[t]);
    __syncthreads();
    order[meta[16 + d] + lb[d] + r] = i;
}

// ---------------- GEMM1: 128x128, BK=32 ----------------
// v8 = v6 with the A-refill moved BETWEEN split and MFMA (zero-register-cost lead):
// once splitA8 consumes RA into ah/al, RA is dead, so the refill loads write RA
// directly and gain one MFMA-cluster (~250cyc) of issue lead over v6 — without
// v7's temps-held-across-MFMA, which spilled (WRITE_SIZE +4.7MB scratch) and
// regressed. sched_barrier(0) pins the loads above the MFMA cluster (rule #18).
// Ledger unchanged from v6: queue at top of iter t = [B(t)4, A(t)4, B(t+1)4,
// A(t+1)4] -> vmcnt(8) drains exactly B(t),A(t); vmcnt(0) only at ks=31.
// B: triple-buffered LDS (3x16KB = 48KB) -> 2-iteration glds lead.
__global__ __launch_bounds__(256, 3)
void dael_gemm1(const int* __restrict__ order, const int* __restrict__ bexp,
                const float* __restrict__ x,
                const short* __restrict__ w1h, const short* __restrict__ w1l,
                const float* __restrict__ b1,
                short* __restrict__ hh, short* __restrict__ hl) {
    const int L = blockIdx.x;
    const int xcd = L & 7, j = L >> 3;
    const int mb = xcd * 17 + (j % 17);
    const int strip = j / 17;
    const int e = bexp[mb];
    if (e < 0) return;
    const int tid = threadIdx.x;
    const int lane = tid & 63, wv = tid >> 6;
    const int quad = lane >> 4, lrow = lane & 15;
    const int r0w = wv * 32;   // wave owns rows [r0w, r0w+32), all 128 cols

    // 3 x 16KB B buffers; epilogue T[128][136] (34816B) reuses
    __shared__ __align__(16) char SMc[49152];

    // A: per-lane sample rows (clamp pad rows to 0 — garbage-but-finite h rows;
    // gemm2 masks the final store by samp>=0)
    int s0 = order[mb * 128 + r0w + lrow];
    int s1 = order[mb * 128 + r0w + 16 + lrow];
    if (s0 < 0) s0 = 0;
    if (s1 < 0) s1 = 0;
    const float* xb0 = x + (size_t)s0 * F1 + quad * 8;
    const float* xb1 = x + (size_t)s1 * F1 + quad * 8;
    // B: staged via global_load_lds
    const short* Bh = w1h + (size_t)((e * 4 + strip) * 32) * 4096 + tid * 8;
    const short* Bl = w1l + (size_t)((e * 4 + strip) * 32) * 4096 + tid * 8;
    const int d0 = tid * 16;

    float4v acc[2][8] = {};
    int offb[8];
    #pragma unroll
    for (int jj = 0; jj < 8; ++jj) offb[jj] = quad * 2048 + (jj * 16 + lrow) * 16;

    float4 ra0[4], ra1[4];
    int c0 = 0, c1 = 16384, c2 = 32768;  // rotating LDS buffer byte offsets

    // prologue, issue order pinned: B(0) glds x4, A(0) x4, B(1) glds x4, A(1) x4
    glds16(Bh,        SMc + d0);
    glds16(Bh + 2048, SMc + 4096 + d0);
    glds16(Bl,        SMc + 8192 + d0);
    glds16(Bl + 2048, SMc + 12288 + d0);
    asm volatile("" ::: "memory");
    ra0[0] = *(const float4*)(xb0);
    ra0[1] = *(const float4*)(xb0 + 4);
    ra0[2] = *(const float4*)(xb1);
    ra0[3] = *(const float4*)(xb1 + 4);
    asm volatile("" ::: "memory");
    glds16(Bh + 4096,        SMc + 16384 + d0);
    glds16(Bh + 4096 + 2048, SMc + 16384 + 4096 + d0);
    glds16(Bl + 4096,        SMc + 16384 + 8192 + d0);
    glds16(Bl + 4096 + 2048, SMc + 16384 + 12288 + d0);
    asm volatile("" ::: "memory");
    ra1[0] = *(const float4*)(xb0 + 32);
    ra1[1] = *(const float4*)(xb0 + 36);
    ra1[2] = *(const float4*)(xb1 + 32);
    ra1[3] = *(const float4*)(xb1 + 36);

#define G1_ITER(KS, RA)                                                        \
    {                                                                          \
        if ((KS) == 31) { asm volatile("s_waitcnt vmcnt(0)" ::: "memory"); }   \
        else            { asm volatile("s_waitcnt vmcnt(8)" ::: "memory"); }   \
        __builtin_amdgcn_s_barrier();                                          \
        asm volatile("" ::: "memory");                                         \
        if ((KS) + 2 < 32) {                                                   \
            const int so_ = ((KS) + 2) * 4096;                                 \
            glds16(Bh + so_,        SMc + c2 + d0);                            \
            glds16(Bh + so_ + 2048, SMc + c2 + 4096 + d0);                     \
            glds16(Bl + so_,        SMc + c2 + 8192 + d0);                     \
            glds16(Bl + so_ + 2048, SMc + c2 + 12288 + d0);                    \
        }                                                                      \
        asm volatile("" ::: "memory");                                         \
        short8 ah[2], al[2];                                                   \
        splitA8(RA[0], RA[1], ah[0], al[0]);                                   \
        splitA8(RA[2], RA[3], ah[1], al[1]);                                   \
        if ((KS) + 2 < 32) {  /* RA dead after split: refill in place, pre-MFMA */ \
            const int ao_ = ((KS) + 2) * 32;                                   \
            RA[0] = *(const float4*)(xb0 + ao_);                               \
            RA[1] = *(const float4*)(xb0 + ao_ + 4);                           \
            RA[2] = *(const float4*)(xb1 + ao_);                               \
            RA[3] = *(const float4*)(xb1 + ao_ + 4);                           \
        }                                                                      \
        __builtin_amdgcn_sched_barrier(0);  /* pin: refill issued before MFMAs */ \
        __builtin_amdgcn_s_setprio(1);                                         \
        _Pragma("unroll")                                                      \
        for (int jj = 0; jj < 8; ++jj) {                                       \
            short8 bh = *(const short8*)(SMc + c0 + offb[jj]);                 \
            short8 bl = *(const short8*)(SMc + c0 + 8192 + offb[jj]);          \
            _Pragma("unroll")                                                  \
            for (int i = 0; i < 2; ++i) {                                      \
                acc[i][jj] = mfma16(ah[i], bh, acc[i][jj]);                    \
                acc[i][jj] = mfma16(ah[i], bl, acc[i][jj]);                    \
                acc[i][jj] = mfma16(al[i], bh, acc[i][jj]);                    \
            }                                                                  \
        }                                                                      \
        __builtin_amdgcn_s_setprio(0);                                         \
        { const int tmp_ = c0; c0 = c1; c1 = c2; c2 = tmp_; }                  \
    }

    for (int kb = 0; kb < 32; kb += 2) {
        G1_ITER(kb,     ra0);
        G1_ITER(kb + 1, ra1);
    }
#undef G1_ITER

    // epilogue: +b1, relu, split; through LDS T[128][136]; store packed h tiles
    float bv[8];
    #pragma unroll
    for (int jj = 0; jj < 8; ++jj)
        bv[jj] = b1[e * F2 + strip * 128 + jj * 16 + lrow];
    short* T = (short*)SMc;
    #pragma unroll
    for (int plane = 0; plane < 2; ++plane) {
        __syncthreads();
        #pragma unroll
        for (int i = 0; i < 2; ++i)
            #pragma unroll
            for (int jj = 0; jj < 8; ++jj)
                #pragma unroll
                for (int r = 0; r < 4; ++r) {
                    const int m = r0w + i * 16 + quad * 4 + r;
                    const int n = jj * 16 + lrow;
                    float hv = fmaxf(acc[i][jj][r] + bv[jj], 0.f);
                    short hi = bf16_rn(hv);
                    T[m * 136 + n] = plane ? bf16_rn(hv - bf16_up(hi)) : hi;
                }
        __syncthreads();
        short* dst = plane ? hl : hh;
        #pragma unroll
        for (int u = 0; u < 8; ++u) {
            const int sidx = tid + 256 * u;          // 0..2047
            const int g = sidx >> 6, m64 = sidx & 63;
            const int mloc = g >> 4, ksl = (g >> 3) & 1, q = g & 7;
            const int m = mloc * 64 + m64;
            const int n = ksl * 64 + q * 8;
            const size_t off = ((size_t)((mb * 2 + mloc) * 8 + strip * 2 + ksl)) * 4096
                               + q * 512 + m64 * 8;
            *(short8*)(dst + off) = *(const short8*)&T[m * 136 + n];
        }
    }
}

// ---------------- GEMM2: 64x64, BK=64, double-buffered; softmax ----------------
__global__ __launch_bounds__(256)
void dael_gemm2(const int* __restrict__ order, const int* __restrict__ bexp,
                const short* __restrict__ hh, const short* __restrict__ hl,
                const short* __restrict__ w2h, const short* __restrict__ w2l,
                const float* __restrict__ b2, float* __restrict__ out) {
    const int b = blockIdx.x;
    const int e = bexp[b >> 1];
    if (e < 0) return;
    const int p0 = b * 64;
    const int tid = threadIdx.x;
    const int lane = tid & 63, wv = tid >> 6;
    const int quad = lane >> 4, lrow = lane & 15;

    __shared__ __align__(16) char SM2[65536];  // 2 x 32KB double buffer; softmax reuses
    __shared__ float inv[64];

    const short* Ah = hh + (size_t)(b * 8) * 4096 + tid * 8;
    const short* Al = hl + (size_t)(b * 8) * 4096 + tid * 8;
    const short* Bh = w2h + (size_t)(e * 8) * 4096 + tid * 8;
    const short* Bl = w2l + (size_t)(e * 8) * 4096 + tid * 8;
    const int d0 = tid * 16;

    float4v acc[4] = {};

    {
        glds16(Ah,        SM2 + d0);
        glds16(Ah + 2048, SM2 + 4096 + d0);
        glds16(Al,        SM2 + 8192 + d0);
        glds16(Al + 2048, SM2 + 12288 + d0);
        glds16(Bh,        SM2 + 16384 + d0);
        glds16(Bh + 2048, SM2 + 20480 + d0);
        glds16(Bl,        SM2 + 24576 + d0);
        glds16(Bl + 2048, SM2 + 28672 + d0);
    }

    for (int ks = 0; ks < 8; ++ks) {
        __syncthreads();
        if (ks + 1 < 8) {
            const int so = (ks + 1) * 4096;
            const int db = ((ks + 1) & 1) * 32768;
            glds16(Ah + so,        SM2 + db + d0);
            glds16(Ah + so + 2048, SM2 + db + 4096 + d0);
            glds16(Al + so,        SM2 + db + 8192 + d0);
            glds16(Al + so + 2048, SM2 + db + 12288 + d0);
            glds16(Bh + so,        SM2 + db + 16384 + d0);
            glds16(Bh + so + 2048, SM2 + db + 20480 + d0);
            glds16(Bl + so,        SM2 + db + 24576 + d0);
            glds16(Bl + so + 2048, SM2 + db + 28672 + d0);
        }
        const int db = (ks & 1) * 32768;
        #pragma unroll
        for (int ksub = 0; ksub < 2; ++ksub) {
            const int qa = (ksub * 4 + quad) * 1024;
            const int ao = db + qa + (wv * 16 + lrow) * 16;
            short8 ahf = *(const short8*)(SM2 + ao);
            short8 alf = *(const short8*)(SM2 + 8192 + ao);
            #pragma unroll
            for (int jj = 0; jj < 4; ++jj) {
                const int bo = db + 16384 + qa + (jj * 16 + lrow) * 16;
                short8 bh = *(const short8*)(SM2 + bo);
                short8 bl = *(const short8*)(SM2 + 8192 + bo);
                acc[jj] = mfma16(ahf, bh, acc[jj]);
                acc[jj] = mfma16(ahf, bl, acc[jj]);
                acc[jj] = mfma16(alf, bh, acc[jj]);
            }
        }
    }

    __syncthreads();
    float* Lx = (float*)SM2;               // [64][68]
    #pragma unroll
    for (int jj = 0; jj < 4; ++jj) {
        const int n = jj * 16 + lrow;
        const float bb = b2[e * NCLS + n];
        #pragma unroll
        for (int r = 0; r < 4; ++r)
            Lx[(wv * 16 + quad * 4 + r) * 68 + n] = acc[jj][r] + bb;
    }
    __syncthreads();
    if (tid < 64) {
        float mx = -3.402823466e38f;
        #pragma unroll 8
        for (int c = 0; c < NCLS; ++c) mx = fmaxf(mx, Lx[tid * 68 + c]);
        float s = 0.f;
        #pragma unroll 8
        for (int c = 0; c < NCLS; ++c) {
            float ev = __expf(Lx[tid * 68 + c] - mx);
            Lx[tid * 68 + c] = ev; s += ev;
        }
        inv[tid] = 1.f / s;
    }
    __syncthreads();
    const int r = tid >> 2, cs = (tid & 3) * 16;
    const int samp = order[p0 + r];
    if (samp >= 0) {
        const float sc = inv[r];
        #pragma unroll
        for (int q = 0; q < 4; ++q) {
            float4 v = *(const float4*)&Lx[r * 68 + cs + q * 4];
            v.x *= sc; v.y *= sc; v.z *= sc; v.w *= sc;
            *(float4*)(out + (size_t)samp * NCLS + cs + q * 4) = v;
        }
    }
}

extern "C" void kernel_launch(void* const* d_in, const int* in_sizes, int n_in,
                              void* d_out, int out_size, void* d_ws, size_t ws_size,
                              hipStream_t stream) {
    const int*   domain = (const int*)d_in[0];
    const float* x      = (const float*)d_in[1];
    const float* W1     = (const float*)d_in[2];
    const float* b1     = (const float*)d_in[3];
    const float* W2     = (const float*)d_in[4];
    const float* b2     = (const float*)d_in[5];
    float* out = (float*)d_out;

    char* ws = (char*)d_ws;
    int*   meta  = (int*)(ws + O_META);
    int*   bexp  = (int*)(ws + O_BEXP);
    int*   order = (int*)(ws + O_ORDER);
    short* w1h   = (short*)(ws + O_W1H);
    short* w1l   = (short*)(ws + O_W1L);
    short* w2h   = (short*)(ws + O_W2H);
    short* w2l   = (short*)(ws + O_W2L);
    short* hh    = (short*)(ws + O_HH);
    short* hl    = (short*)(ws + O_HL);

    dael_init_pack<<<NPW1 + NPW2, 256, 0, stream>>>(domain, meta, order,
                                                    W1, w1h, w1l, W2, w2h, w2l);
    dael_plan<<<1, 256, 0, stream>>>(meta, bexp);
    dael_scatter<<<64, 256, 0, stream>>>(domain, meta, order);
    dael_gemm1<<<NBG1, 256, 0, stream>>>(order, bexp, x, w1h, w1l, b1, hh, hl);
    dael_gemm2<<<NBG2, 256, 0, stream>>>(order, bexp, hh, hl, w2h, w2l, b2, out);
}